// Round 1
// baseline (1305.145 us; speedup 1.0000x reference)
//
#include <hip/hip_runtime.h>
#include <hip/hip_bf16.h>

#define B_ 2
#define S_ 2048
#define D_ 1024
#define H_ 16
#define DH_ 64

typedef __attribute__((ext_vector_type(8))) short bf16x8;
typedef __attribute__((ext_vector_type(4))) float f32x4;

__device__ __forceinline__ ushort f2b(float f){
  __hip_bfloat16 h = __float2bfloat16(f);
  return *reinterpret_cast<ushort*>(&h);
}

// ---------------- f32 -> bf16 convert (n multiple of 2048) ----------------
__global__ void k_f32_to_bf16(const float* __restrict__ in, ushort* __restrict__ out, int n){
  int i = (blockIdx.x*blockDim.x + threadIdx.x)*8;
  if (i >= n) return;
  float4 v0 = *(const float4*)(in + i);
  float4 v1 = *(const float4*)(in + i + 4);
  uint4 o;
  o.x = f2b(v0.x) | ((unsigned)f2b(v0.y)<<16);
  o.y = f2b(v0.z) | ((unsigned)f2b(v0.w)<<16);
  o.z = f2b(v1.x) | ((unsigned)f2b(v1.y)<<16);
  o.w = f2b(v1.z) | ((unsigned)f2b(v1.w)<<16);
  *(uint4*)(out + i) = o;
}

// ---------------- transpose [R][C] f32 -> [C][R] bf16 ----------------
__global__ __launch_bounds__(256) void k_transpose_bf16(const float* __restrict__ in,
                                                        ushort* __restrict__ out, int R, int C){
  __shared__ float tile[32][33];
  int nbx = C/32;
  int bx = blockIdx.x % nbx, by = blockIdx.x / nbx;
  int c0 = bx*32, r0 = by*32;
  int tx = threadIdx.x & 31, ty = threadIdx.x >> 5; // ty 0..7
  #pragma unroll
  for (int i=0;i<4;i++)
    tile[ty + i*8][tx] = in[(size_t)(r0 + ty + i*8)*C + c0 + tx];
  __syncthreads();
  #pragma unroll
  for (int i=0;i<4;i++)
    out[(size_t)(c0 + ty + i*8)*R + r0 + tx] = f2b(tile[tx][ty + i*8]);
}

// ---------------- bf16 MFMA GEMM: C[M,N] = A[M,K] * BT[N,K]^T + bias ----------------
// 128x128 tile, BK=32, 256 threads (4 waves, 2x2), 4x4 16x16x32 frags per wave.
template<int F32OUT>
__global__ __launch_bounds__(256) void k_gemm_bt(const ushort* __restrict__ A,
                                                 const ushort* __restrict__ BT,
                                                 const float* __restrict__ bias,
                                                 void* __restrict__ Cp,
                                                 int M, int N, int K){
  __shared__ ushort As[128*32];
  __shared__ ushort Bs[128*32];
  const int tid = threadIdx.x;
  const int nbn = N >> 7;
  const int bm = blockIdx.x / nbn, bn = blockIdx.x % nbn;
  const int m0 = bm << 7, n0 = bn << 7;
  const int wave = tid >> 6, lane = tid & 63;
  const int wm = (wave >> 1) << 6, wn = (wave & 1) << 6;
  const int lr = lane & 15, lq = lane >> 4;

  f32x4 acc[4][4] = {};

  // staging: chunk c -> row=c>>2, kc=c&3 (16B chunks of 8 bf16); thread owns c=tid, tid+256
  const int r0c = tid >> 2, k0c = tid & 3;
  const int r1c = r0c + 64;
  const int wofs0 = r0c*32 + ((k0c ^ (r0c & 3)) << 3);  // slot-XOR swizzle
  const int wofs1 = r1c*32 + ((k0c ^ (r1c & 3)) << 3);

  const ushort* Ag0 = A  + (size_t)(m0 + r0c)*K + k0c*8;
  const ushort* Ag1 = A  + (size_t)(m0 + r1c)*K + k0c*8;
  const ushort* Bg0 = BT + (size_t)(n0 + r0c)*K + k0c*8;
  const ushort* Bg1 = BT + (size_t)(n0 + r1c)*K + k0c*8;

  for (int kt = 0; kt < K; kt += 32){
    uint4 a0 = *(const uint4*)(Ag0 + kt);
    uint4 a1 = *(const uint4*)(Ag1 + kt);
    uint4 b0 = *(const uint4*)(Bg0 + kt);
    uint4 b1 = *(const uint4*)(Bg1 + kt);
    __syncthreads();                 // previous iter's LDS reads done
    *(uint4*)&As[wofs0] = a0;
    *(uint4*)&As[wofs1] = a1;
    *(uint4*)&Bs[wofs0] = b0;
    *(uint4*)&Bs[wofs1] = b1;
    __syncthreads();
    bf16x8 af[4], bfr[4];
    #pragma unroll
    for (int i=0;i<4;i++){
      int ra = wm + i*16 + lr;
      af[i]  = *(bf16x8*)&As[ra*32 + ((lq ^ (ra & 3)) << 3)];
      int rb = wn + i*16 + lr;
      bfr[i] = *(bf16x8*)&Bs[rb*32 + ((lq ^ (rb & 3)) << 3)];
    }
    #pragma unroll
    for (int mi=0;mi<4;mi++)
      #pragma unroll
      for (int ni=0;ni<4;ni++)
        acc[mi][ni] = __builtin_amdgcn_mfma_f32_16x16x32_bf16(af[mi], bfr[ni], acc[mi][ni], 0, 0, 0);
  }
  // epilogue: D lane mapping col=lane&15, row=(lane>>4)*4+r (m89-verified)
  #pragma unroll
  for (int mi=0;mi<4;mi++){
    #pragma unroll
    for (int ni=0;ni<4;ni++){
      int col = n0 + wn + ni*16 + lr;
      float bv = bias[col];
      #pragma unroll
      for (int r=0;r<4;r++){
        int row = m0 + wm + mi*16 + lq*4 + r;
        float v = acc[mi][ni][r] + bv;
        if (F32OUT) ((float*)Cp)[(size_t)row*N + col] = v;
        else        ((ushort*)Cp)[(size_t)row*N + col] = f2b(v);
      }
    }
  }
}

// ---------------- fused causal attention, fp32, flash-style ----------------
// grid: B*H*(S/64) blocks, 256 threads. Thread (g=tid>>2, j=tid&3): row g of the
// q-tile; owns keys t = 4*tt+j and output dims [16j,16j+16).
__global__ __launch_bounds__(256) void k_attn(const ushort* __restrict__ Qb,
                                              const ushort* __restrict__ Kb,
                                              const ushort* __restrict__ Vb,
                                              ushort* __restrict__ Ob){
  __shared__ float Ks[64*68];
  __shared__ float Vs[64*68];
  const int bx = blockIdx.x;
  const int qt = bx & 31, h = (bx >> 5) & 15, b = bx >> 9;
  const int q0 = qt << 6;
  const int tid = threadIdx.x;
  const int g = tid >> 2, j = tid & 3;
  const int lane = tid & 63;
  const int myd = j << 4;

  // q row -> 64 f32 regs, pre-scaled by 1/sqrt(DH)=0.125
  float q[64];
  {
    const ushort* Qrow = Qb + (size_t)(b*S_ + q0 + g)*1024 + h*64;
    #pragma unroll
    for (int c=0;c<8;c++){
      uint4 u = *(const uint4*)(Qrow + c*8);
      unsigned w[4] = {u.x,u.y,u.z,u.w};
      #pragma unroll
      for (int e=0;e<4;e++){
        q[c*8 + e*2]     = __uint_as_float(w[e]<<16)        * 0.125f;
        q[c*8 + e*2 + 1] = __uint_as_float(w[e]&0xffff0000u)* 0.125f;
      }
    }
  }

  float outv[16];
  #pragma unroll
  for (int i=0;i<16;i++) outv[i] = 0.f;
  float m = -1e30f, l = 0.f;

  const size_t stg_base = (size_t)(b*S_)*1024 + h*64 + (tid&3)*16;

  for (int kt = 0; kt <= qt; kt++){
    const int t0 = kt << 6;
    { // stage K,V tile (bf16 global -> f32 LDS, row pad 68 floats)
      const ushort* Kg = Kb + stg_base + (size_t)(t0 + g)*1024;
      const ushort* Vg = Vb + stg_base + (size_t)(t0 + g)*1024;
      uint4 ku0 = *(const uint4*)(Kg);
      uint4 ku1 = *(const uint4*)(Kg + 8);
      uint4 vu0 = *(const uint4*)(Vg);
      uint4 vu1 = *(const uint4*)(Vg + 8);
      __syncthreads();               // previous iter's LDS reads done
      float* kd = &Ks[g*68 + myd];
      float* vd = &Vs[g*68 + myd];
      unsigned kw[8] = {ku0.x,ku0.y,ku0.z,ku0.w,ku1.x,ku1.y,ku1.z,ku1.w};
      unsigned vw[8] = {vu0.x,vu0.y,vu0.z,vu0.w,vu1.x,vu1.y,vu1.z,vu1.w};
      #pragma unroll
      for (int e=0;e<8;e++){
        kd[e*2]   = __uint_as_float(kw[e]<<16);
        kd[e*2+1] = __uint_as_float(kw[e]&0xffff0000u);
        vd[e*2]   = __uint_as_float(vw[e]<<16);
        vd[e*2+1] = __uint_as_float(vw[e]&0xffff0000u);
      }
      __syncthreads();
    }
    // scores for my 16 keys
    float s[16];
    #pragma unroll
    for (int tt=0;tt<16;tt++){
      int t = (tt<<2) + j;
      const float* kr = &Ks[t*68];
      float a0=0.f,a1=0.f,a2=0.f,a3=0.f;
      #pragma unroll
      for (int dd=0;dd<16;dd++){
        float4 kv = *(const float4*)(kr + dd*4);
        a0 += kv.x * q[dd*4];
        a1 += kv.y * q[dd*4+1];
        a2 += kv.z * q[dd*4+2];
        a3 += kv.w * q[dd*4+3];
      }
      float sc = (a0+a1)+(a2+a3);
      if (kt == qt && t > g) sc = -1e30f;   // causal
      s[tt] = sc;
    }
    // online softmax (quad = one q row)
    float mt = s[0];
    #pragma unroll
    for (int tt=1;tt<16;tt++) mt = fmaxf(mt, s[tt]);
    mt = fmaxf(mt, __shfl_xor(mt, 1, 64));
    mt = fmaxf(mt, __shfl_xor(mt, 2, 64));
    float mnew = fmaxf(m, mt);
    float corr = __expf(m - mnew);
    float ls = 0.f;
    #pragma unroll
    for (int tt=0;tt<16;tt++){ s[tt] = __expf(s[tt] - mnew); ls += s[tt]; }
    ls += __shfl_xor(ls, 1, 64);
    ls += __shfl_xor(ls, 2, 64);
    l = l*corr + ls;
    m = mnew;
    #pragma unroll
    for (int i=0;i<16;i++) outv[i] *= corr;
    // PV: broadcast p across quad, accumulate my d-slice
    const int qbase = lane & ~3;
    #pragma unroll
    for (int tt=0;tt<16;tt++){
      #pragma unroll
      for (int j2=0;j2<4;j2++){
        float p = __shfl(s[tt], qbase + j2, 64);
        const float* vr = &Vs[((tt<<2)+j2)*68 + myd];
        float4 v0 = *(const float4*)(vr);
        float4 v1 = *(const float4*)(vr+4);
        float4 v2 = *(const float4*)(vr+8);
        float4 v3 = *(const float4*)(vr+12);
        outv[0]  += p*v0.x; outv[1]  += p*v0.y; outv[2]  += p*v0.z; outv[3]  += p*v0.w;
        outv[4]  += p*v1.x; outv[5]  += p*v1.y; outv[6]  += p*v1.z; outv[7]  += p*v1.w;
        outv[8]  += p*v2.x; outv[9]  += p*v2.y; outv[10] += p*v2.z; outv[11] += p*v2.w;
        outv[12] += p*v3.x; outv[13] += p*v3.y; outv[14] += p*v3.z; outv[15] += p*v3.w;
      }
    }
  }
  const float inv = 1.0f / l;
  unsigned ow[8];
  #pragma unroll
  for (int e=0;e<8;e++)
    ow[e] = f2b(outv[e*2]*inv) | ((unsigned)f2b(outv[e*2+1]*inv)<<16);
  uint4 o0, o1;
  o0.x=ow[0]; o0.y=ow[1]; o0.z=ow[2]; o0.w=ow[3];
  o1.x=ow[4]; o1.y=ow[5]; o1.z=ow[6]; o1.w=ow[7];
  ushort* Op = Ob + (size_t)(b*S_ + q0 + g)*1024 + h*64 + myd;
  *(uint4*)(Op)     = o0;
  *(uint4*)(Op + 8) = o1;
}

// ---------------- launch ----------------
extern "C" void kernel_launch(void* const* d_in, const int* in_sizes, int n_in,
                              void* d_out, int out_size, void* d_ws, size_t ws_size,
                              hipStream_t stream){
  const float* x  = (const float*)d_in[0];
  // d_in[1] = mask (tril) — implemented analytically, unused
  const float* Wq = (const float*)d_in[2];
  const float* bq = (const float*)d_in[3];
  const float* Wk = (const float*)d_in[4];
  const float* bk = (const float*)d_in[5];
  const float* Wv = (const float*)d_in[6];
  const float* bv = (const float*)d_in[7];
  const float* Wo = (const float*)d_in[8];
  const float* bo = (const float*)d_in[9];

  char* ws = (char*)d_ws;
  const size_t MB = 1024u*1024u;
  ushort* xb   = (ushort*)(ws + 0);       // 8MB; reused as attended after QKV GEMMs
  ushort* WqT  = (ushort*)(ws + 8*MB);
  ushort* WkT  = (ushort*)(ws + 10*MB);
  ushort* WvT  = (ushort*)(ws + 12*MB);
  ushort* WoT  = (ushort*)(ws + 14*MB);
  ushort* Qb   = (ushort*)(ws + 16*MB);
  ushort* Kb   = (ushort*)(ws + 24*MB);
  ushort* Vb   = (ushort*)(ws + 32*MB);   // total 40MB
  ushort* attb = xb;

  const int MN = B_*S_;        // 4096
  const int n_x = MN*D_;       // 4194304

  k_f32_to_bf16<<<dim3(n_x/(256*8)), dim3(256), 0, stream>>>(x, xb, n_x);
  k_transpose_bf16<<<dim3(1024), dim3(256), 0, stream>>>(Wq, WqT, 1024, 1024);
  k_transpose_bf16<<<dim3(1024), dim3(256), 0, stream>>>(Wk, WkT, 1024, 1024);
  k_transpose_bf16<<<dim3(1024), dim3(256), 0, stream>>>(Wv, WvT, 1024, 1024);
  k_transpose_bf16<<<dim3(1024), dim3(256), 0, stream>>>(Wo, WoT, 1024, 1024);

  dim3 ggrid((MN/128)*(1024/128));
  k_gemm_bt<0><<<ggrid, dim3(256), 0, stream>>>(xb, WqT, bq, Qb, MN, 1024, 1024);
  k_gemm_bt<0><<<ggrid, dim3(256), 0, stream>>>(xb, WkT, bk, Kb, MN, 1024, 1024);
  k_gemm_bt<0><<<ggrid, dim3(256), 0, stream>>>(xb, WvT, bv, Vb, MN, 1024, 1024);

  k_attn<<<dim3(B_*H_*(S_/64)), dim3(256), 0, stream>>>(Qb, Kb, Vb, attb);

  k_gemm_bt<1><<<ggrid, dim3(256), 0, stream>>>(attb, WoT, bo, (float*)d_out, MN, 1024, 1024);
}

// Round 2
// 167.436 us; speedup vs baseline: 7.7949x; 7.7949x over previous
//
#include <hip/hip_runtime.h>
#include <hip/hip_bf16.h>

#define B_ 2
#define S_ 2048
#define D_ 1024
#define H_ 16
#define DH_ 64

typedef __attribute__((ext_vector_type(8))) short bf16x8;
typedef __attribute__((ext_vector_type(4))) float f32x4;

__device__ __forceinline__ ushort f2b(float f){
  __hip_bfloat16 h = __float2bfloat16(f);
  return *reinterpret_cast<ushort*>(&h);
}

// ---------------- f32 -> bf16 convert ----------------
__global__ void k_f32_to_bf16(const float* __restrict__ in, ushort* __restrict__ out, int n){
  int i = (blockIdx.x*blockDim.x + threadIdx.x)*8;
  if (i >= n) return;
  float4 v0 = *(const float4*)(in + i);
  float4 v1 = *(const float4*)(in + i + 4);
  uint4 o;
  o.x = f2b(v0.x) | ((unsigned)f2b(v0.y)<<16);
  o.y = f2b(v0.z) | ((unsigned)f2b(v0.w)<<16);
  o.z = f2b(v1.x) | ((unsigned)f2b(v1.y)<<16);
  o.w = f2b(v1.z) | ((unsigned)f2b(v1.w)<<16);
  *(uint4*)(out + i) = o;
}

// ---------------- transpose [R][C] f32 -> [C][R] bf16 (weights) ----------------
__global__ __launch_bounds__(256) void k_transpose_bf16(const float* __restrict__ in,
                                                        ushort* __restrict__ out, int R, int C){
  __shared__ float tile[32][33];
  int nbx = C/32;
  int bx = blockIdx.x % nbx, by = blockIdx.x / nbx;
  int c0 = bx*32, r0 = by*32;
  int tx = threadIdx.x & 31, ty = threadIdx.x >> 5;
  #pragma unroll
  for (int i=0;i<4;i++)
    tile[ty + i*8][tx] = in[(size_t)(r0 + ty + i*8)*C + c0 + tx];
  __syncthreads();
  #pragma unroll
  for (int i=0;i<4;i++)
    out[(size_t)(c0 + ty + i*8)*R + r0 + tx] = f2b(tile[tx][ty + i*8]);
}

// ---------------- bf16 MFMA GEMM: C[M,N] = A[M,K] * BT[N,K]^T + bias ----------------
// OUT: 0 = bf16 row-major, 1 = f32 row-major, 2 = bf16 V-transposed:
//      Vt[(b*1024 + col)][s] layout, i.e. per (b,h): [dh=64][S=2048]
template<int OUT>
__global__ __launch_bounds__(256) void k_gemm_bt(const ushort* __restrict__ A,
                                                 const ushort* __restrict__ BT,
                                                 const float* __restrict__ bias,
                                                 void* __restrict__ Cp,
                                                 int M, int N, int K){
  __shared__ ushort As[128*32];
  __shared__ ushort Bs[128*32];
  const int tid = threadIdx.x;
  const int nbn = N >> 7;
  const int bm = blockIdx.x / nbn, bn = blockIdx.x % nbn;
  const int m0 = bm << 7, n0 = bn << 7;
  const int wave = tid >> 6, lane = tid & 63;
  const int wm = (wave >> 1) << 6, wn = (wave & 1) << 6;
  const int lr = lane & 15, lq = lane >> 4;

  f32x4 acc[4][4] = {};

  const int r0c = tid >> 2, k0c = tid & 3;
  const int r1c = r0c + 64;
  const int wofs0 = r0c*32 + ((k0c ^ (r0c & 3)) << 3);
  const int wofs1 = r1c*32 + ((k0c ^ (r1c & 3)) << 3);

  const ushort* Ag0 = A  + (size_t)(m0 + r0c)*K + k0c*8;
  const ushort* Ag1 = A  + (size_t)(m0 + r1c)*K + k0c*8;
  const ushort* Bg0 = BT + (size_t)(n0 + r0c)*K + k0c*8;
  const ushort* Bg1 = BT + (size_t)(n0 + r1c)*K + k0c*8;

  for (int kt = 0; kt < K; kt += 32){
    uint4 a0 = *(const uint4*)(Ag0 + kt);
    uint4 a1 = *(const uint4*)(Ag1 + kt);
    uint4 b0 = *(const uint4*)(Bg0 + kt);
    uint4 b1 = *(const uint4*)(Bg1 + kt);
    __syncthreads();
    *(uint4*)&As[wofs0] = a0;
    *(uint4*)&As[wofs1] = a1;
    *(uint4*)&Bs[wofs0] = b0;
    *(uint4*)&Bs[wofs1] = b1;
    __syncthreads();
    bf16x8 af[4], bfr[4];
    #pragma unroll
    for (int i=0;i<4;i++){
      int ra = wm + i*16 + lr;
      af[i]  = *(bf16x8*)&As[ra*32 + ((lq ^ (ra & 3)) << 3)];
      int rb = wn + i*16 + lr;
      bfr[i] = *(bf16x8*)&Bs[rb*32 + ((lq ^ (rb & 3)) << 3)];
    }
    #pragma unroll
    for (int mi=0;mi<4;mi++)
      #pragma unroll
      for (int ni=0;ni<4;ni++)
        acc[mi][ni] = __builtin_amdgcn_mfma_f32_16x16x32_bf16(af[mi], bfr[ni], acc[mi][ni], 0, 0, 0);
  }
  #pragma unroll
  for (int mi=0;mi<4;mi++){
    #pragma unroll
    for (int ni=0;ni<4;ni++){
      int col = n0 + wn + ni*16 + lr;
      float bv = bias[col];
      if (OUT == 2){
        int row0 = m0 + wm + mi*16 + lq*4;     // token of r=0 (4 consecutive tokens)
        int bb = row0 >> 11;
        int srow = row0 & 2047;
        uint2 pk;
        pk.x = f2b(acc[mi][ni][0]+bv) | ((unsigned)f2b(acc[mi][ni][1]+bv)<<16);
        pk.y = f2b(acc[mi][ni][2]+bv) | ((unsigned)f2b(acc[mi][ni][3]+bv)<<16);
        *(uint2*)&((ushort*)Cp)[((size_t)(bb*1024 + col))*2048 + srow] = pk;
      } else {
        #pragma unroll
        for (int r=0;r<4;r++){
          int row = m0 + wm + mi*16 + lq*4 + r;
          float v = acc[mi][ni][r] + bv;
          if (OUT == 1) ((float*)Cp)[(size_t)row*N + col] = v;
          else          ((ushort*)Cp)[(size_t)row*N + col] = f2b(v);
        }
      }
    }
  }
}

// ---------------- MFMA flash attention ----------------
// Grid: 1024 blocks = 32 (reversed q-tiles of 64) x 32 (b*H+h). 256 thr = 4 waves.
// Wave wq owns q rows [q0+wq*16, q0+wq*16+16). KV tiles of 64 keys.
// Swapped QK^T: S^T = mfma(K, Q) -> row=key, col=q. Softmax over keys =
// in-lane reduce + shfl_xor(16,32). P bounced through wave-private swizzled LDS
// to become the PV A-operand. V is staged from the pre-transposed Vt buffer.
__device__ __forceinline__ bf16x8 lds_frag(const ushort* base, int row, int colbytes){
  return *(const bf16x8*)((const char*)base + row*128 + (colbytes ^ ((row & 7) << 4)));
}

__global__ __launch_bounds__(256) void k_attn_mfma(const ushort* __restrict__ Qb,
                                                   const ushort* __restrict__ Kb,
                                                   const ushort* __restrict__ Vtg,
                                                   ushort* __restrict__ Ob){
  __shared__ ushort Ks[64*64];
  __shared__ ushort Vs[64*64];
  __shared__ ushort Ps[4][16*64];
  const int bx = blockIdx.x;
  const int qt = 31 - (bx >> 5);          // heavy tiles dispatch first
  const int bh = bx & 31;
  const int h = bh & 15, b = bh >> 4;
  const int q0 = qt << 6;
  const int tid = threadIdx.x;
  const int wq = tid >> 6;
  const int lane = tid & 63;
  const int ql = lane & 15;
  const int g = lane >> 4;

  // Q fragments (B-operand), held in registers for the whole loop
  bf16x8 Qf[2];
  {
    const ushort* qp = Qb + (size_t)(b*S_ + q0 + wq*16 + ql)*1024 + h*64 + g*8;
    Qf[0] = *(const bf16x8*)(qp);
    Qf[1] = *(const bf16x8*)(qp + 32);
  }

  float mst = -1e30f, lst = 0.f;          // per-q stats (q = ql, replicated over g)
  f32x4 acc[4] = {};                      // O accum: row=q=(g*4+r), col=dh=ni*16+ql

  // staging: 512 16B chunks per tile; thread owns chunks tid, tid+256
  const int r0c = tid >> 3, cc0 = tid & 7;
  const int r1c = r0c + 32, cc1 = cc0;
  const int ofs0 = r0c*128 + ((cc0*16) ^ ((r0c & 7) << 4));
  const int ofs1 = r1c*128 + ((cc1*16) ^ ((r1c & 7) << 4));
  const ushort* Kp0 = Kb  + (size_t)(b*S_ + r0c)*1024 + h*64 + cc0*8;
  const ushort* Kp1 = Kb  + (size_t)(b*S_ + r1c)*1024 + h*64 + cc1*8;
  const ushort* Vp0 = Vtg + (size_t)(bh*64 + r0c)*2048 + cc0*8;
  const ushort* Vp1 = Vtg + (size_t)(bh*64 + r1c)*2048 + cc1*8;

  uint4 ka = *(const uint4*)(Kp0);
  uint4 kc = *(const uint4*)(Kp1);
  uint4 va = *(const uint4*)(Vp0);
  uint4 vc = *(const uint4*)(Vp1);

  char* Pb = (char*)Ps + wq*2048;

  for (int kt = 0; ; ++kt){
    __syncthreads();                       // previous tile's LDS reads done
    *(uint4*)((char*)Ks + ofs0) = ka;
    *(uint4*)((char*)Ks + ofs1) = kc;
    *(uint4*)((char*)Vs + ofs0) = va;
    *(uint4*)((char*)Vs + ofs1) = vc;
    __syncthreads();
    if (kt < qt){                          // prefetch next tile (hides under compute)
      ka = *(const uint4*)(Kp0 + (size_t)(kt+1)*64*1024);
      kc = *(const uint4*)(Kp1 + (size_t)(kt+1)*64*1024);
      va = *(const uint4*)(Vp0 + (kt+1)*64);
      vc = *(const uint4*)(Vp1 + (kt+1)*64);
    }

    // ---- QK^T (swapped): sf[ki] row=key ki*16+g*4+r, col=q=ql ----
    f32x4 sf[4] = {};
    __builtin_amdgcn_s_setprio(1);
    #pragma unroll
    for (int ks=0; ks<2; ++ks){
      #pragma unroll
      for (int ki=0; ki<4; ++ki){
        bf16x8 kf = lds_frag(Ks, ki*16 + ql, ks*64 + g*16);
        sf[ki] = __builtin_amdgcn_mfma_f32_16x16x32_bf16(kf, Qf[ks], sf[ki], 0, 0, 0);
      }
    }
    __builtin_amdgcn_s_setprio(0);

    // ---- softmax over keys ----
    float s[16];
    #pragma unroll
    for (int ki=0; ki<4; ++ki)
      #pragma unroll
      for (int r=0; r<4; ++r)
        s[ki*4+r] = sf[ki][r] * 0.125f;
    if (kt == qt){
      const int th = wq*16 + ql;
      #pragma unroll
      for (int ki=0; ki<4; ++ki)
        #pragma unroll
        for (int r=0; r<4; ++r)
          if (ki*16 + g*4 + r > th) s[ki*4+r] = -1e30f;
    }
    float mt = s[0];
    #pragma unroll
    for (int i=1; i<16; ++i) mt = fmaxf(mt, s[i]);
    mt = fmaxf(mt, __shfl_xor(mt, 16, 64));
    mt = fmaxf(mt, __shfl_xor(mt, 32, 64));
    float mnew = fmaxf(mst, mt);
    float corr = __expf(mst - mnew);
    mst = mnew;
    float ls = 0.f;
    #pragma unroll
    for (int i=0; i<16; ++i){ s[i] = __expf(s[i] - mnew); ls += s[i]; }
    ls += __shfl_xor(ls, 16, 64);
    ls += __shfl_xor(ls, 32, 64);
    lst = lst*corr + ls;
    #pragma unroll
    for (int r=0; r<4; ++r){
      float cr = __shfl(corr, g*4 + r, 64);
      #pragma unroll
      for (int ni=0; ni<4; ++ni) acc[ni][r] *= cr;
    }

    // ---- P -> wave-private LDS (row=q, keys packed 4-wide) ----
    #pragma unroll
    for (int ki=0; ki<4; ++ki){
      uint2 uu;
      uu.x = f2b(s[ki*4+0]) | ((unsigned)f2b(s[ki*4+1])<<16);
      uu.y = f2b(s[ki*4+2]) | ((unsigned)f2b(s[ki*4+3])<<16);
      *(uint2*)(Pb + ql*128 + ((ki*32 + g*8) ^ ((ql & 7) << 4))) = uu;
    }

    // ---- PV: O[q][dh] += P * V ----
    __builtin_amdgcn_s_setprio(1);
    #pragma unroll
    for (int ks=0; ks<2; ++ks){
      bf16x8 pf = *(const bf16x8*)(Pb + ql*128 + (((ks*64 + g*16)) ^ ((ql & 7) << 4)));
      #pragma unroll
      for (int ni=0; ni<4; ++ni){
        int dh = ni*16 + ql;
        bf16x8 vf = lds_frag(Vs, dh, ks*64 + g*16);
        acc[ni] = __builtin_amdgcn_mfma_f32_16x16x32_bf16(pf, vf, acc[ni], 0, 0, 0);
      }
    }
    __builtin_amdgcn_s_setprio(0);

    if (kt == qt) break;
  }

  float invl = 1.0f / lst;
  ushort* Op = Ob + (size_t)(b*S_ + q0 + wq*16)*1024 + h*64;
  #pragma unroll
  for (int r=0; r<4; ++r){
    float ir = __shfl(invl, g*4 + r, 64);
    #pragma unroll
    for (int ni=0; ni<4; ++ni)
      Op[(size_t)(g*4 + r)*1024 + ni*16 + ql] = f2b(acc[ni][r] * ir);
  }
}

// ---------------- launch ----------------
extern "C" void kernel_launch(void* const* d_in, const int* in_sizes, int n_in,
                              void* d_out, int out_size, void* d_ws, size_t ws_size,
                              hipStream_t stream){
  const float* x  = (const float*)d_in[0];
  const float* Wq = (const float*)d_in[2];
  const float* bq = (const float*)d_in[3];
  const float* Wk = (const float*)d_in[4];
  const float* bk = (const float*)d_in[5];
  const float* Wv = (const float*)d_in[6];
  const float* bv = (const float*)d_in[7];
  const float* Wo = (const float*)d_in[8];
  const float* bo = (const float*)d_in[9];

  char* ws = (char*)d_ws;
  const size_t MB = 1024u*1024u;
  ushort* xb   = (ushort*)(ws + 0);       // 8MB; reused as attended
  ushort* WqT  = (ushort*)(ws + 8*MB);
  ushort* WkT  = (ushort*)(ws + 10*MB);
  ushort* WvT  = (ushort*)(ws + 12*MB);
  ushort* WoT  = (ushort*)(ws + 14*MB);
  ushort* Qb   = (ushort*)(ws + 16*MB);
  ushort* Kb   = (ushort*)(ws + 24*MB);
  ushort* Vtg  = (ushort*)(ws + 32*MB);   // V pre-transposed: [(b*16+h)*64+dh][2048]
  ushort* attb = xb;

  const int MN = B_*S_;
  const int n_x = MN*D_;

  k_f32_to_bf16<<<dim3(n_x/(256*8)), dim3(256), 0, stream>>>(x, xb, n_x);
  k_transpose_bf16<<<dim3(1024), dim3(256), 0, stream>>>(Wq, WqT, 1024, 1024);
  k_transpose_bf16<<<dim3(1024), dim3(256), 0, stream>>>(Wk, WkT, 1024, 1024);
  k_transpose_bf16<<<dim3(1024), dim3(256), 0, stream>>>(Wv, WvT, 1024, 1024);
  k_transpose_bf16<<<dim3(1024), dim3(256), 0, stream>>>(Wo, WoT, 1024, 1024);

  dim3 ggrid((MN/128)*(1024/128));
  k_gemm_bt<0><<<ggrid, dim3(256), 0, stream>>>(xb, WqT, bq, Qb, MN, 1024, 1024);
  k_gemm_bt<0><<<ggrid, dim3(256), 0, stream>>>(xb, WkT, bk, Kb, MN, 1024, 1024);
  k_gemm_bt<2><<<ggrid, dim3(256), 0, stream>>>(xb, WvT, bv, Vtg, MN, 1024, 1024);

  k_attn_mfma<<<dim3(1024), dim3(256), 0, stream>>>(Qb, Kb, Vtg, attb);

  k_gemm_bt<1><<<ggrid, dim3(256), 0, stream>>>(attb, WoT, bo, (float*)d_out, MN, 1024, 1024);
}

// Round 3
// 136.696 us; speedup vs baseline: 9.5478x; 1.2249x over previous
//
#include <hip/hip_runtime.h>
#include <hip/hip_bf16.h>

#define B_ 2
#define S_ 2048
#define D_ 1024
#define H_ 16
#define DH_ 64

typedef __attribute__((ext_vector_type(8))) short bf16x8;
typedef __attribute__((ext_vector_type(4))) float f32x4;

// 0.125 (1/sqrt(DH)) * log2(e): Q pre-scale so attention scores are in exp2 domain
#define QSCALE 0.18033688011112042f

__device__ __forceinline__ ushort f2b(float f){
  __hip_bfloat16 h = __float2bfloat16(f);
  return *reinterpret_cast<ushort*>(&h);
}

__device__ __forceinline__ void gload16(const ushort* g, ushort* l){
  __builtin_amdgcn_global_load_lds((const __attribute__((address_space(1))) unsigned*)g,
                                   (__attribute__((address_space(3))) unsigned*)l, 16, 0, 0);
}

// ---------------- f32 -> bf16 convert ----------------
__global__ void k_f32_to_bf16(const float* __restrict__ in, ushort* __restrict__ out, int n){
  int i = (blockIdx.x*blockDim.x + threadIdx.x)*8;
  if (i >= n) return;
  float4 v0 = *(const float4*)(in + i);
  float4 v1 = *(const float4*)(in + i + 4);
  uint4 o;
  o.x = f2b(v0.x) | ((unsigned)f2b(v0.y)<<16);
  o.y = f2b(v0.z) | ((unsigned)f2b(v0.w)<<16);
  o.z = f2b(v1.x) | ((unsigned)f2b(v1.y)<<16);
  o.w = f2b(v1.z) | ((unsigned)f2b(v1.w)<<16);
  *(uint4*)(out + i) = o;
}

// ---------------- transpose [R][C] f32 -> [C][R] bf16 (weights) ----------------
__global__ __launch_bounds__(256) void k_transpose_bf16(const float* __restrict__ in,
                                                        ushort* __restrict__ out, int R, int C){
  __shared__ float tile[32][33];
  int nbx = C/32;
  int bx = blockIdx.x % nbx, by = blockIdx.x / nbx;
  int c0 = bx*32, r0 = by*32;
  int tx = threadIdx.x & 31, ty = threadIdx.x >> 5;
  #pragma unroll
  for (int i=0;i<4;i++)
    tile[ty + i*8][tx] = in[(size_t)(r0 + ty + i*8)*C + c0 + tx];
  __syncthreads();
  #pragma unroll
  for (int i=0;i<4;i++)
    out[(size_t)(c0 + ty + i*8)*R + r0 + tx] = f2b(tile[tx][ty + i*8]);
}

// ---------------- bf16 MFMA GEMM: C[M,N] = A[M,K] * BT[N,K]^T + bias ----------------
// OUT=1: f32 row-major (out projection).
// OUT=3: fused QKV routing: col<1024 -> Qb bf16 (scaled by QSCALE); col<2048 -> Kb bf16;
//        col>=2048 -> Vt transposed [(b*1024 + dhcol)][2048].
//        Cp = Qb base; Kb = Qb + 4M elems; Vt = Qb + 8M elems.
// Staging via global_load_lds(16B): LDS linear, global source chunk pre-swizzled so the
// read-side XOR swizzle sees layout slot(row,s) = global chunk s^(row&3).
template<int OUT>
__global__ __launch_bounds__(256) void k_gemm_bt(const ushort* __restrict__ A,
                                                 const ushort* __restrict__ BT,
                                                 const float* __restrict__ bias,
                                                 void* __restrict__ Cp,
                                                 int M, int N, int K){
  __shared__ ushort As[128*32];
  __shared__ ushort Bs[128*32];
  const int tid = threadIdx.x;
  const int nbn = N >> 7;
  const int bm = blockIdx.x / nbn, bn = blockIdx.x % nbn;
  const int m0 = bm << 7, n0 = bn << 7;
  const int wave = tid >> 6, lane = tid & 63;
  const int wm = (wave >> 1) << 6, wn = (wave & 1) << 6;
  const int lr = lane & 15, lq = lane >> 4;

  f32x4 acc[4][4] = {};

  // issue0: chunk c0 = tid; issue1: chunk c1 = tid+256. LDS byte addr = c*16 (linear).
  // row = c>>2, slot = c&3; source global chunk k = slot ^ (row&3).
  const int c0 = tid,        r0 = c0 >> 2, k0 = (c0 & 3) ^ (r0 & 3);
  const int c1 = tid + 256,  r1 = c1 >> 2, k1 = (c1 & 3) ^ (r1 & 3);
  const ushort* Ag0 = A  + (size_t)(m0 + r0)*K + k0*8;
  const ushort* Ag1 = A  + (size_t)(m0 + r1)*K + k1*8;
  const ushort* Bg0 = BT + (size_t)(n0 + r0)*K + k0*8;
  const ushort* Bg1 = BT + (size_t)(n0 + r1)*K + k1*8;
  ushort* La0 = &As[c0*8];  ushort* La1 = &As[c1*8];
  ushort* Lb0 = &Bs[c0*8];  ushort* Lb1 = &Bs[c1*8];

  for (int kt = 0; kt < K; kt += 32){
    __syncthreads();                 // previous iter's LDS reads done
    gload16(Ag0 + kt, La0);
    gload16(Ag1 + kt, La1);
    gload16(Bg0 + kt, Lb0);
    gload16(Bg1 + kt, Lb1);
    __syncthreads();                 // vmcnt(0) drain + barrier
    bf16x8 af[4], bfr[4];
    #pragma unroll
    for (int i=0;i<4;i++){
      int ra = wm + i*16 + lr;
      af[i]  = *(bf16x8*)&As[ra*32 + ((lq ^ (ra & 3)) << 3)];
      int rb = wn + i*16 + lr;
      bfr[i] = *(bf16x8*)&Bs[rb*32 + ((lq ^ (rb & 3)) << 3)];
    }
    __builtin_amdgcn_s_setprio(1);
    #pragma unroll
    for (int mi=0;mi<4;mi++)
      #pragma unroll
      for (int ni=0;ni<4;ni++)
        acc[mi][ni] = __builtin_amdgcn_mfma_f32_16x16x32_bf16(af[mi], bfr[ni], acc[mi][ni], 0, 0, 0);
    __builtin_amdgcn_s_setprio(0);
  }
  // epilogue: D lane mapping col=lane&15, row=(lane>>4)*4+r
  #pragma unroll
  for (int mi=0;mi<4;mi++){
    #pragma unroll
    for (int ni=0;ni<4;ni++){
      int col = n0 + wn + ni*16 + lr;
      float bv = bias[col];
      int row0 = m0 + wm + mi*16 + lq*4;
      if (OUT == 1){
        #pragma unroll
        for (int r=0;r<4;r++)
          ((float*)Cp)[(size_t)(row0+r)*N + col] = acc[mi][ni][r] + bv;
      } else { // OUT == 3
        ushort* Qb = (ushort*)Cp;
        if (col < 1024){
          #pragma unroll
          for (int r=0;r<4;r++)
            Qb[(size_t)(row0+r)*1024 + col] = f2b((acc[mi][ni][r] + bv) * QSCALE);
        } else if (col < 2048){
          ushort* Kb = Qb + (4u<<20);
          #pragma unroll
          for (int r=0;r<4;r++)
            Kb[(size_t)(row0+r)*1024 + (col-1024)] = f2b(acc[mi][ni][r] + bv);
        } else {
          ushort* Vt = Qb + (8u<<20);
          int bb = row0 >> 11, srow = row0 & 2047;
          uint2 pk;
          pk.x = f2b(acc[mi][ni][0]+bv) | ((unsigned)f2b(acc[mi][ni][1]+bv)<<16);
          pk.y = f2b(acc[mi][ni][2]+bv) | ((unsigned)f2b(acc[mi][ni][3]+bv)<<16);
          *(uint2*)&Vt[((size_t)(bb*1024 + (col-2048)))*2048 + srow] = pk;
        }
      }
    }
  }
}

// ---------------- MFMA flash attention ----------------
// Grid: 1024 blocks = 32 (reversed q-tiles of 64) x 32 (b*H+h). 256 thr = 4 waves.
// Swapped QK^T (scores born in log2 domain via Q pre-scale). Defer-max (THR=8).
__device__ __forceinline__ bf16x8 lds_frag(const ushort* base, int row, int colbytes){
  return *(const bf16x8*)((const char*)base + row*128 + (colbytes ^ ((row & 7) << 4)));
}

__global__ __launch_bounds__(256) void k_attn_mfma(const ushort* __restrict__ Qb,
                                                   const ushort* __restrict__ Kb,
                                                   const ushort* __restrict__ Vtg,
                                                   ushort* __restrict__ Ob){
  __shared__ ushort Ks[64*64];
  __shared__ ushort Vs[64*64];
  __shared__ ushort Ps[4][16*64];
  const int bx = blockIdx.x;
  const int qt = 31 - (bx >> 5);          // heavy tiles dispatch first
  const int bh = bx & 31;
  const int h = bh & 15, b = bh >> 4;
  const int q0 = qt << 6;
  const int tid = threadIdx.x;
  const int wq = tid >> 6;
  const int lane = tid & 63;
  const int ql = lane & 15;
  const int g = lane >> 4;

  bf16x8 Qf[2];
  {
    const ushort* qp = Qb + (size_t)(b*S_ + q0 + wq*16 + ql)*1024 + h*64 + g*8;
    Qf[0] = *(const bf16x8*)(qp);
    Qf[1] = *(const bf16x8*)(qp + 32);
  }

  float mst = -1e30f, lst = 0.f;
  f32x4 acc[4] = {};

  const int r0c = tid >> 3, cc0 = tid & 7;
  const int r1c = r0c + 32;
  const int ofs0 = r0c*128 + ((cc0*16) ^ ((r0c & 7) << 4));
  const int ofs1 = r1c*128 + ((cc0*16) ^ ((r1c & 7) << 4));
  const ushort* Kp0 = Kb  + (size_t)(b*S_ + r0c)*1024 + h*64 + cc0*8;
  const ushort* Kp1 = Kb  + (size_t)(b*S_ + r1c)*1024 + h*64 + cc0*8;
  const ushort* Vp0 = Vtg + (size_t)(bh*64 + r0c)*2048 + cc0*8;
  const ushort* Vp1 = Vtg + (size_t)(bh*64 + r1c)*2048 + cc0*8;

  uint4 ka = *(const uint4*)(Kp0);
  uint4 kc = *(const uint4*)(Kp1);
  uint4 va = *(const uint4*)(Vp0);
  uint4 vc = *(const uint4*)(Vp1);

  char* Pb = (char*)Ps + wq*2048;

  for (int kt = 0; ; ++kt){
    __syncthreads();
    *(uint4*)((char*)Ks + ofs0) = ka;
    *(uint4*)((char*)Ks + ofs1) = kc;
    *(uint4*)((char*)Vs + ofs0) = va;
    *(uint4*)((char*)Vs + ofs1) = vc;
    __syncthreads();
    if (kt < qt){
      ka = *(const uint4*)(Kp0 + (size_t)(kt+1)*64*1024);
      kc = *(const uint4*)(Kp1 + (size_t)(kt+1)*64*1024);
      va = *(const uint4*)(Vp0 + (kt+1)*64);
      vc = *(const uint4*)(Vp1 + (kt+1)*64);
    }

    // ---- QK^T (swapped): sf[ki] row=key ki*16+g*4+r, col=q=ql ----
    f32x4 sf[4] = {};
    __builtin_amdgcn_s_setprio(1);
    #pragma unroll
    for (int ks=0; ks<2; ++ks){
      #pragma unroll
      for (int ki=0; ki<4; ++ki){
        bf16x8 kf = lds_frag(Ks, ki*16 + ql, ks*64 + g*16);
        sf[ki] = __builtin_amdgcn_mfma_f32_16x16x32_bf16(kf, Qf[ks], sf[ki], 0, 0, 0);
      }
    }
    __builtin_amdgcn_s_setprio(0);

    // ---- online softmax (log2 domain) ----
    float s[16];
    #pragma unroll
    for (int ki=0; ki<4; ++ki)
      #pragma unroll
      for (int r=0; r<4; ++r)
        s[ki*4+r] = sf[ki][r];
    if (kt == qt){
      const int th = wq*16 + ql;
      #pragma unroll
      for (int ki=0; ki<4; ++ki)
        #pragma unroll
        for (int r=0; r<4; ++r)
          if (ki*16 + g*4 + r > th) s[ki*4+r] = -1e30f;
    }
    float t0 = fmaxf(fmaxf(s[0], s[1]), s[2]);
    float t1 = fmaxf(fmaxf(s[3], s[4]), s[5]);
    float t2 = fmaxf(fmaxf(s[6], s[7]), s[8]);
    float t3 = fmaxf(fmaxf(s[9], s[10]), s[11]);
    float t4 = fmaxf(fmaxf(s[12], s[13]), s[14]);
    float mt = fmaxf(fmaxf(fmaxf(t0, t1), fmaxf(t2, t3)), fmaxf(t4, s[15]));
    mt = fmaxf(mt, __shfl_xor(mt, 16, 64));
    mt = fmaxf(mt, __shfl_xor(mt, 32, 64));
    if (__any(mt > mst + 8.f)){           // defer-max: rescale only on real growth
      float mnew = fmaxf(mst, mt);
      float corr = exp2f(mst - mnew);
      mst = mnew;
      lst *= corr;
      #pragma unroll
      for (int r=0; r<4; ++r){
        float cr = __shfl(corr, g*4 + r, 64);
        #pragma unroll
        for (int ni=0; ni<4; ++ni) acc[ni][r] *= cr;
      }
    }
    float ls = 0.f;
    #pragma unroll
    for (int i=0; i<16; ++i){ s[i] = exp2f(s[i] - mst); ls += s[i]; }
    ls += __shfl_xor(ls, 16, 64);
    ls += __shfl_xor(ls, 32, 64);
    lst += ls;

    // ---- P -> wave-private LDS (row=q, keys packed 4-wide) ----
    #pragma unroll
    for (int ki=0; ki<4; ++ki){
      uint2 uu;
      uu.x = f2b(s[ki*4+0]) | ((unsigned)f2b(s[ki*4+1])<<16);
      uu.y = f2b(s[ki*4+2]) | ((unsigned)f2b(s[ki*4+3])<<16);
      *(uint2*)(Pb + ql*128 + ((ki*32 + g*8) ^ ((ql & 7) << 4))) = uu;
    }

    // ---- PV ----
    __builtin_amdgcn_s_setprio(1);
    #pragma unroll
    for (int ks=0; ks<2; ++ks){
      bf16x8 pf = *(const bf16x8*)(Pb + ql*128 + (((ks*64 + g*16)) ^ ((ql & 7) << 4)));
      #pragma unroll
      for (int ni=0; ni<4; ++ni){
        bf16x8 vf = lds_frag(Vs, ni*16 + ql, ks*64 + g*16);
        acc[ni] = __builtin_amdgcn_mfma_f32_16x16x32_bf16(pf, vf, acc[ni], 0, 0, 0);
      }
    }
    __builtin_amdgcn_s_setprio(0);

    if (kt == qt) break;
  }

  float invl = 1.0f / lst;
  ushort* Op = Ob + (size_t)(b*S_ + q0 + wq*16)*1024 + h*64;
  #pragma unroll
  for (int r=0; r<4; ++r){
    float ir = __shfl(invl, g*4 + r, 64);
    #pragma unroll
    for (int ni=0; ni<4; ++ni)
      Op[(size_t)(g*4 + r)*1024 + ni*16 + ql] = f2b(acc[ni][r] * ir);
  }
}

// ---------------- launch ----------------
extern "C" void kernel_launch(void* const* d_in, const int* in_sizes, int n_in,
                              void* d_out, int out_size, void* d_ws, size_t ws_size,
                              hipStream_t stream){
  const float* x  = (const float*)d_in[0];
  const float* Wq = (const float*)d_in[2];
  const float* bq = (const float*)d_in[3];
  const float* Wk = (const float*)d_in[4];
  const float* bk = (const float*)d_in[5];
  const float* Wv = (const float*)d_in[6];
  const float* bv = (const float*)d_in[7];
  const float* Wo = (const float*)d_in[8];
  const float* bo = (const float*)d_in[9];

  char* ws = (char*)d_ws;
  const size_t MB = 1024u*1024u;
  ushort* xb    = (ushort*)(ws + 0);        // 8MB; reused as attended
  ushort* WqkvT = (ushort*)(ws + 8*MB);     // [3072][1024] bf16 = 6MB
  ushort* WoT   = (ushort*)(ws + 14*MB);    // 2MB
  ushort* Qb    = (ushort*)(ws + 16*MB);    // 8MB
  ushort* Kb    = (ushort*)(ws + 24*MB);    // 8MB
  ushort* Vtg   = (ushort*)(ws + 32*MB);    // 8MB, [(b*16+h)*64+dh][2048]
  float*  bqkv  = (float*)(ws + 40*MB);     // 12KB
  ushort* attb  = xb;

  const int MN = B_*S_;
  const int n_x = MN*D_;

  hipMemcpyAsync(bqkv,        bq, 1024*sizeof(float), hipMemcpyDeviceToDevice, stream);
  hipMemcpyAsync(bqkv + 1024, bk, 1024*sizeof(float), hipMemcpyDeviceToDevice, stream);
  hipMemcpyAsync(bqkv + 2048, bv, 1024*sizeof(float), hipMemcpyDeviceToDevice, stream);

  k_f32_to_bf16<<<dim3(n_x/(256*8)), dim3(256), 0, stream>>>(x, xb, n_x);
  k_transpose_bf16<<<dim3(1024), dim3(256), 0, stream>>>(Wq, WqkvT,             1024, 1024);
  k_transpose_bf16<<<dim3(1024), dim3(256), 0, stream>>>(Wk, WqkvT + 1024*1024, 1024, 1024);
  k_transpose_bf16<<<dim3(1024), dim3(256), 0, stream>>>(Wv, WqkvT + 2048*1024, 1024, 1024);
  k_transpose_bf16<<<dim3(1024), dim3(256), 0, stream>>>(Wo, WoT,               1024, 1024);

  // fused QKV projection: M=4096, N=3072, K=1024
  k_gemm_bt<3><<<dim3((MN/128)*(3072/128)), dim3(256), 0, stream>>>(xb, WqkvT, bqkv, Qb, MN, 3072, 1024);

  k_attn_mfma<<<dim3(1024), dim3(256), 0, stream>>>(Qb, Kb, Vtg, attb);

  k_gemm_bt<1><<<dim3((MN/128)*(1024/128)), dim3(256), 0, stream>>>(attb, WoT, bo, (float*)d_out, MN, 1024, 1024);
}